// Round 12
// baseline (318.369 us; speedup 1.0000x reference)
//
#include <hip/hip_runtime.h>
#include <hip/hip_bf16.h>
#include <stdint.h>
#include <stddef.h>

// Problem constants
#define B_ 32
#define N_ 1024
#define C_ 768
#define H_ 12
#define D_ 64
#define M_ (B_*N_)     // 32768 rows
#define TC_ (3*C_)     // 2304 qkv cols

typedef __bf16 bf16_t;
typedef __attribute__((ext_vector_type(8))) __bf16 bf16x8;
typedef __attribute__((ext_vector_type(4))) __bf16 bf16x4;
typedef __attribute__((ext_vector_type(4))) float  f32x4;

#define MFMA16(a,b,c) __builtin_amdgcn_mfma_f32_16x16x32_bf16(a,b,c,0,0,0)

__device__ __forceinline__ void lds_load16(const void* g, void* l) {
  __builtin_amdgcn_global_load_lds(
      (const __attribute__((address_space(1))) void*)g,
      (__attribute__((address_space(3))) void*)l, 16, 0, 0);
}

// ---------------------------------------------------------------- converts
__global__ void cvt_bf16(const float* __restrict__ in, bf16_t* __restrict__ out, int n) {
  int i = (blockIdx.x * 256 + threadIdx.x) * 8;
  if (i >= n) return;
  const float4 a = *(const float4*)(in + i);
  const float4 b = *(const float4*)(in + i + 4);
  bf16x8 r;
  r[0]=(bf16_t)a.x; r[1]=(bf16_t)a.y; r[2]=(bf16_t)a.z; r[3]=(bf16_t)a.w;
  r[4]=(bf16_t)b.x; r[5]=(bf16_t)b.y; r[6]=(bf16_t)b.z; r[7]=(bf16_t)b.w;
  *(bf16x8*)(out + i) = r;
}

// out[c][r] = bf16(in[r][c]); grid (Cc/32, R/32), 256 threads
__global__ void transpose_cvt(const float* __restrict__ in, bf16_t* __restrict__ out,
                              int R, int Cc) {
  __shared__ float t[32][33];
  const int c0 = blockIdx.x * 32, r0 = blockIdx.y * 32;
  const int tx = threadIdx.x & 31, ty = threadIdx.x >> 5;  // ty 0..7
  #pragma unroll
  for (int k = 0; k < 4; ++k)
    t[ty + k*8][tx] = in[(size_t)(r0 + ty + k*8)*Cc + c0 + tx];
  __syncthreads();
  #pragma unroll
  for (int k = 0; k < 4; ++k)
    out[(size_t)(c0 + ty + k*8)*R + r0 + tx] = (bf16_t)t[tx][ty + k*8];
}

// ---------------------------------------------------------------- GEMM1 256x256, BK=64, 8 waves
// (unchanged from R11 — 8-phase schedule; G1 plateau is structural, see journal)
template<int MODE>
__global__ __launch_bounds__(512, 2)
void gemm_bt(const bf16_t* __restrict__ A, const bf16_t* __restrict__ BT,
             const float* __restrict__ bias, float* __restrict__ Cout,
             bf16_t* __restrict__ qh,
             bf16_t* __restrict__ kthi, bf16_t* __restrict__ vthi,
             int nbx)
{
  __shared__ __align__(16) char smem[131072];

  const int nwg = gridDim.x;
  const int cpx = nwg >> 3;                       // nwg % 8 == 0
  const int bid = blockIdx.x;
  const int swz = (bid & 7) * cpx + (bid >> 3);   // bijective XCD chunking
  const int bx  = swz % nbx;
  const int by  = swz / nbx;

  const int tid  = threadIdx.x;
  const int wave = tid >> 6;
  const int lane = tid & 63;
  const int rowBase = by * 256;
  const int colBase = bx * 256;
  const int wr = wave >> 2;          // 0..1  (row block of 128)
  const int wc = wave & 3;           // 0..3  (col block of 64)
  const int fr = lane & 15;
  const int hi = lane >> 4;          // 0..3  (8-elem k-subgroup)
  const int b   = rowBase >> 10;
  const int nn0 = rowBase & (N_ - 1);

  const int rls  = tid >> 3;
  const int scol = (((tid & 7) ^ ((tid >> 3) & 7)) << 3);
  const bf16_t *ApS0, *ApS1, *BpS0, *BpS1;
  size_t AKT, AJS;
  if (MODE == 3) {
    const bf16_t* ab = A + (size_t)b * (H_*N_*D_);
    ApS0 = ab + (size_t)(nn0 + rls) * D_ + scol;
    ApS1 = ab + (size_t)(nn0 + 128 + rls) * D_ + scol;
    AKT = (size_t)N_ * D_;  AJS = (size_t)64 * D_;
  } else {
    ApS0 = A + (size_t)(rowBase + rls) * 768 + scol;
    ApS1 = A + (size_t)(rowBase + 128 + rls) * 768 + scol;
    AKT = 64;  AJS = (size_t)64 * 768;
  }
  const size_t bts = (MODE == 3) ? (size_t)b * C_ * C_ : 0;
  BpS0 = BT + bts + (size_t)(colBase + rls) * 768 + scol;
  BpS1 = BT + bts + (size_t)(colBase + 128 + rls) * 768 + scol;
  const size_t BJS = (size_t)64 * 768;

  const int axr  = fr & 7;
  const int chx0 = ((0 + hi) ^ axr) << 4;
  const int chx1 = ((4 + hi) ^ axr) << 4;
  const int abase = wr*16384 + fr*128;
  const int bbase = 32768 + (wc>>1)*16384 + ((wc&1)*64 + fr)*128;

#define RA(BUF,M,KK) (*(const bf16x8*)(smem + (BUF)*65536 + abase + (M)*2048 + ((KK)?chx1:chx0)))
#define RB(BUF,N,KK) (*(const bf16x8*)(smem + (BUF)*65536 + bbase + (N)*2048 + ((KK)?chx1:chx0)))

#define SGA(BUF,H,T) do{ \
    const bf16_t* p_ = (H) ? ApS1 : ApS0; \
    lds_load16(p_ + (size_t)(T)*AKT,       smem + (BUF)*65536 + (H)*16384 + tid*16); \
    lds_load16(p_ + (size_t)(T)*AKT + AJS, smem + (BUF)*65536 + (H)*16384 + 8192 + tid*16); \
  }while(0)
#define SGB(BUF,H,T) do{ \
    const bf16_t* p_ = (H) ? BpS1 : BpS0; \
    lds_load16(p_ + (size_t)(T)*64,       smem + (BUF)*65536 + 32768 + (H)*16384 + tid*16); \
    lds_load16(p_ + (size_t)(T)*64 + BJS, smem + (BUF)*65536 + 32768 + (H)*16384 + 8192 + tid*16); \
  }while(0)

#define SBR() __builtin_amdgcn_sched_barrier(0)
#define BARX() do{ SBR(); __builtin_amdgcn_s_barrier(); SBR(); }while(0)
#define LG0() do{ asm volatile("s_waitcnt lgkmcnt(0)":::"memory"); SBR(); }while(0)
#define VMW4() do{ asm volatile("s_waitcnt vmcnt(4)":::"memory"); SBR(); }while(0)
#define VMW0() do{ asm volatile("s_waitcnt vmcnt(0)":::"memory"); SBR(); }while(0)

  f32x4 acc[8][4];
  #pragma unroll
  for (int m = 0; m < 8; ++m)
    #pragma unroll
    for (int n = 0; n < 4; ++n) acc[m][n] = f32x4{0.f,0.f,0.f,0.f};

  bf16x8 bfr00, bfr01, bfr10, bfr11, bfr20, bfr21, bfr30, bfr31;

#define PHASE(BUF, Q, STAGES, ENDV) do{ \
    if ((Q) == 0) { \
      bfr00 = RB(BUF,0,0); bfr01 = RB(BUF,0,1); \
      bfr10 = RB(BUF,1,0); bfr11 = RB(BUF,1,1); \
      bfr20 = RB(BUF,2,0); bfr21 = RB(BUF,2,1); \
      bfr30 = RB(BUF,3,0); bfr31 = RB(BUF,3,1); \
    } \
    bf16x8 a00 = RA(BUF,2*(Q)+0,0), a01 = RA(BUF,2*(Q)+0,1); \
    bf16x8 a10 = RA(BUF,2*(Q)+1,0), a11 = RA(BUF,2*(Q)+1,1); \
    STAGES; \
    BARX(); LG0(); \
    __builtin_amdgcn_s_setprio(1); \
    acc[2*(Q)+0][0]=MFMA16(a00,bfr00,acc[2*(Q)+0][0]); acc[2*(Q)+0][0]=MFMA16(a01,bfr01,acc[2*(Q)+0][0]); \
    acc[2*(Q)+0][1]=MFMA16(a00,bfr10,acc[2*(Q)+0][1]); acc[2*(Q)+0][1]=MFMA16(a01,bfr11,acc[2*(Q)+0][1]); \
    acc[2*(Q)+0][2]=MFMA16(a00,bfr20,acc[2*(Q)+0][2]); acc[2*(Q)+0][2]=MFMA16(a01,bfr21,acc[2*(Q)+0][2]); \
    acc[2*(Q)+0][3]=MFMA16(a00,bfr30,acc[2*(Q)+0][3]); acc[2*(Q)+0][3]=MFMA16(a01,bfr31,acc[2*(Q)+0][3]); \
    acc[2*(Q)+1][0]=MFMA16(a10,bfr00,acc[2*(Q)+1][0]); acc[2*(Q)+1][0]=MFMA16(a11,bfr01,acc[2*(Q)+1][0]); \
    acc[2*(Q)+1][1]=MFMA16(a10,bfr10,acc[2*(Q)+1][1]); acc[2*(Q)+1][1]=MFMA16(a11,bfr11,acc[2*(Q)+1][1]); \
    acc[2*(Q)+1][2]=MFMA16(a10,bfr20,acc[2*(Q)+1][2]); acc[2*(Q)+1][2]=MFMA16(a11,bfr21,acc[2*(Q)+1][2]); \
    acc[2*(Q)+1][3]=MFMA16(a10,bfr30,acc[2*(Q)+1][3]); acc[2*(Q)+1][3]=MFMA16(a11,bfr31,acc[2*(Q)+1][3]); \
    __builtin_amdgcn_s_setprio(0); SBR(); \
    ENDV; \
    BARX(); \
  }while(0)

  // prologue: tile 0 (all 4 halves) -> buf0; B(1) -> buf1. 12 loads/thread.
  SGA(0,0,0); SGA(0,1,0); SGB(0,0,0); SGB(0,1,0); SGB(1,0,1); SGB(1,1,1);
  VMW4(); BARX();

  #pragma unroll 1
  for (int i = 0; i < 5; ++i) {
    const int t0 = 2*i;
    PHASE(0,0, { SGA(1,0,t0+1); },                     );
    PHASE(0,1, { SGA(1,1,t0+1); SGB(0,0,t0+2); },      );
    PHASE(0,2, { SGB(0,1,t0+2); },                     );
    PHASE(0,3, { },                                    VMW4());
    PHASE(1,0, { SGA(0,0,t0+2); },                     );
    PHASE(1,1, { SGA(0,1,t0+2); },                     );
    PHASE(1,2, { SGB(1,0,t0+3); },                     );
    PHASE(1,3, { SGB(1,1,t0+3); },                     VMW4());
  }
  // peeled final iteration: tiles 10 (buf0), 11 (buf1); only A(11) left to stage.
  PHASE(0,0, { SGA(1,0,11); },  );
  PHASE(0,1, { SGA(1,1,11); },  );
  PHASE(0,2, { },               );
  PHASE(0,3, { },               VMW0());
  PHASE(1,0, { },               );
  PHASE(1,1, { },               );
  PHASE(1,2, { },               );
  PHASE(1,3, { },               );

#undef PHASE
#undef SGA
#undef SGB
#undef RA
#undef RB
#undef VMW4
#undef VMW0
#undef LG0
#undef BARX
#undef SBR

  // ---------------------------------------------------------------- epilogue
  if (MODE == 3) {
    #pragma unroll
    for (int n = 0; n < 4; ++n) {
      const int gc = colBase + wc*64 + n*16 + fr;
      const float bb = bias[gc];
      #pragma unroll
      for (int m = 0; m < 8; ++m) {
        const int gr = rowBase + wr*128 + m*16 + ((lane >> 4) << 2);
        #pragma unroll
        for (int j = 0; j < 4; ++j)
          Cout[(size_t)(gr + j)*C_ + gc] = acc[m][n][j] + bb;
      }
    }
  } else {
    __syncthreads();                       // main-loop LDS dead; reuse
    bf16_t* tile = (bf16_t*)smem;          // [64 cols][pitch 260 rows] = 33.3 KB
    const int s = colBase / C_;            // 0=q 1=k 2=v (uniform per block)
    #pragma unroll 1
    for (int ch = 0; ch < 4; ++ch) {       // 64-col chunks of the 256-wide block
      if (ch) __syncthreads();
      if (wc == ch) {
        #pragma unroll
        for (int n = 0; n < 4; ++n) {
          const int cl = n*16 + fr;                        // 0..63
          const float bb = bias[colBase + ch*64 + cl];
          #pragma unroll
          for (int m = 0; m < 8; ++m) {
            const int r0 = wr*128 + m*16 + ((lane >> 4) << 2);
            bf16x4 hv;
            hv[0]=(bf16_t)(acc[m][n][0]+bb); hv[1]=(bf16_t)(acc[m][n][1]+bb);
            hv[2]=(bf16_t)(acc[m][n][2]+bb); hv[3]=(bf16_t)(acc[m][n][3]+bb);
            *(bf16x4*)&tile[cl*260 + r0] = hv;
          }
        }
      }
      __syncthreads();
      const int gcol0 = colBase + ch*64;
      if (s == 0) {
        const int h = gcol0 >> 6;
        const int r = tid >> 1, hh = tid & 1;
        bf16_t* dst = qh + (((size_t)b*H_ + h)*N_ + nn0 + r)*D_ + hh*32;
        #pragma unroll
        for (int i0 = 0; i0 < 32; i0 += 8) {
          bf16x8 vv;
          #pragma unroll
          for (int i = 0; i < 8; ++i) vv[i] = tile[(hh*32 + i0 + i)*260 + r];
          *(bf16x8*)&dst[i0] = vv;
        }
      } else {
        const int rem = gcol0 - s*C_;
        const int h = rem >> 6;
        const int d = tid >> 3, nq = (tid & 7)*32;
        bf16_t* dst = (s == 1 ? kthi : vthi)
                      + (((size_t)b*H_ + h)*D_ + d)*N_ + nn0 + nq;
        #pragma unroll
        for (int i0 = 0; i0 < 32; i0 += 8)
          *(bf16x8*)&dst[i0] = *(const bf16x8*)&tile[d*260 + nq + i0];
      }
    }
  }
}

// ---------------------------------------------------------------- GEMM2 128x128, 16x16x32, 4 waves
// out[gr][gc] = sum_k qh_gather[gr][k] * w2t_b[gc][k] + bias[gc]
// R2-proven 2-barrier inner loop + R4-proven MODE-3 gather addressing.
// Grid 6*256 = 1536 (6 exact CU-rounds); 34KB LDS -> 3-4 blocks/CU (overlap regime).
// fp32 epilogue via LDS transpose -> contiguous 128B stores (kills 1.6x write amp).
__global__ __launch_bounds__(256, 2)
void gemm2_128(const bf16_t* __restrict__ A, const bf16_t* __restrict__ BT,
               const float* __restrict__ bias, float* __restrict__ Cout, int nbx)
{
  __shared__ __align__(16) char smem[34816];
  bf16_t* As = (bf16_t*)smem;            // [128][32]
  bf16_t* Bs = (bf16_t*)(smem + 8192);   // [128][32]
  float*  tile = (float*)smem;           // epilogue: [64 cols][pitch 130] f32 (33.3KB)

  const int nwg = gridDim.x;
  const int cpx = nwg >> 3;                       // 1536/8 = 192
  const int bid = blockIdx.x;
  const int swz = (bid & 7) * cpx + (bid >> 3);   // bijective XCD chunking
  const int bx  = swz % nbx;
  const int by  = swz / nbx;

  const int tid  = threadIdx.x;
  const int wave = tid >> 6;
  const int lane = tid & 63;
  const int rowBase = by * 128;
  const int colBase = bx * 128;
  const int wr = (wave >> 1) * 64;
  const int wc = (wave &  1) * 64;
  const int fr = lane & 15;
  const int fo = (lane >> 4) * 8;
  const int e  = tid * 8;
  const int r0t = e >> 5;    // staging row within 64-row half
  const int c0t = e & 31;
  const int b   = rowBase >> 10;
  const int nn0 = rowBase & (N_ - 1);

  // A = qh gathered: row gr -> qh[b][h=k0/64][nn0+r][k0%64 + c0t]
  const bf16_t* Ap = A + (size_t)b * (H_*N_*D_) + (size_t)(nn0 + r0t) * D_ + c0t;
  const bf16_t* Bp = BT + (size_t)b * C_ * C_ + (size_t)(colBase + r0t) * 768 + c0t;

  f32x4 acc[4][4] = {{0.f,0.f,0.f,0.f}};

  for (int k0 = 0; k0 < 768; k0 += 32) {
    const bf16_t* a0 = Ap + ((size_t)(k0 >> 6) << 16) + (k0 & 32);
    lds_load16(a0,                        &As[wave*512]);
    lds_load16(a0 + (size_t)64*D_,        &As[2048 + wave*512]);
    lds_load16(Bp + k0,                   &Bs[wave*512]);
    lds_load16(Bp + (size_t)64*768 + k0,  &Bs[2048 + wave*512]);
    __syncthreads();
    bf16x8 af[4], bfv[4];
    #pragma unroll
    for (int m = 0; m < 4; ++m) af[m]  = *(const bf16x8*)&As[(wr + m*16 + fr)*32 + fo];
    #pragma unroll
    for (int n = 0; n < 4; ++n) bfv[n] = *(const bf16x8*)&Bs[(wc + n*16 + fr)*32 + fo];
    #pragma unroll
    for (int m = 0; m < 4; ++m)
      #pragma unroll
      for (int n = 0; n < 4; ++n)
        acc[m][n] = MFMA16(af[m], bfv[n], acc[m][n]);
    __syncthreads();
  }

  // ---- fp32 epilogue via LDS transpose: 2 chunks of 64 cols ----
  #pragma unroll 1
  for (int ch = 0; ch < 2; ++ch) {
    __syncthreads();
    if ((wave & 1) == ch) {              // waves with wc == ch*64 own these cols
      #pragma unroll
      for (int n = 0; n < 4; ++n) {
        const int cl = n*16 + fr;        // 0..63 within chunk
        const float bb = bias[colBase + ch*64 + cl];
        #pragma unroll
        for (int m = 0; m < 4; ++m) {
          const int r0 = wr + m*16 + ((lane >> 4) << 2);
          #pragma unroll
          for (int j = 0; j < 4; ++j)
            tile[cl*130 + r0 + j] = acc[m][n][j] + bb;
        }
      }
    }
    __syncthreads();
    // store: thread t -> row r=t>>1 (0..127), col-half hh=t&1 (32 cols = 128B)
    const int r = tid >> 1, hh = tid & 1;
    float* dst = Cout + (size_t)(rowBase + r) * C_ + colBase + ch*64 + hh*32;
    #pragma unroll
    for (int i0 = 0; i0 < 32; i0 += 4) {
      float4 v;
      v.x = tile[(hh*32 + i0 + 0)*130 + r];
      v.y = tile[(hh*32 + i0 + 1)*130 + r];
      v.z = tile[(hh*32 + i0 + 2)*130 + r];
      v.w = tile[(hh*32 + i0 + 3)*130 + r];
      *(float4*)&dst[i0] = v;
    }
  }
}

// ---------------------------------------------------------------- stage 2: logits + softmax
// attnT[bh][e][d] = P[d][e], P = softmax_e( sum_n kt[d][n]*vt[e][n] / 8 )
__global__ __launch_bounds__(256, 2)
void attn_softmax_k(const bf16_t* __restrict__ kthi, const bf16_t* __restrict__ vthi,
                    bf16_t* __restrict__ attnT)
{
  __shared__ float tile[64][65];
  __shared__ float invs[64];
  const int bh = blockIdx.x;
  const int tid = threadIdx.x, wave = tid >> 6, lane = tid & 63;
  const int fr = lane & 15, fo = (lane >> 4) * 8;
  const size_t base = (size_t)bh * D_ * N_;
  f32x4 acc[4][4] = {{0.f,0.f,0.f,0.f}};
  const int k0lo = wave * 256;   // split-K across 4 waves
  #pragma unroll 1
  for (int k0 = k0lo; k0 < k0lo + 256; k0 += 32) {
    bf16x8 ah[4], bhv[4];
    #pragma unroll
    for (int m = 0; m < 4; ++m)
      ah[m] = *(const bf16x8*)&kthi[base + (size_t)(m*16 + fr)*N_ + k0 + fo];
    #pragma unroll
    for (int n = 0; n < 4; ++n)
      bhv[n] = *(const bf16x8*)&vthi[base + (size_t)(n*16 + fr)*N_ + k0 + fo];
    #pragma unroll
    for (int m = 0; m < 4; ++m)
      #pragma unroll
      for (int n = 0; n < 4; ++n)
        acc[m][n] = MFMA16(ah[m], bhv[n], acc[m][n]);
  }
  // cross-wave reduce into LDS
  for (int w = 0; w < 4; ++w) {
    if (wave == w) {
      #pragma unroll
      for (int m = 0; m < 4; ++m)
        #pragma unroll
        for (int n = 0; n < 4; ++n) {
          const int row = m*16 + ((lane >> 4) << 2);
          const int col = n*16 + fr;
          #pragma unroll
          for (int j = 0; j < 4; ++j) {
            if (w == 0) tile[row+j][col]  = acc[m][n][j];
            else        tile[row+j][col] += acc[m][n][j];
          }
        }
    }
    __syncthreads();
  }
  // row softmax (scale 1/8), one thread per row d
  if (tid < 64) {
    float mx = -3.0e38f;
    #pragma unroll
    for (int c = 0; c < 64; ++c) mx = fmaxf(mx, tile[tid][c]);
    mx *= 0.125f;
    float ssum = 0.f;
    #pragma unroll
    for (int c = 0; c < 64; ++c) {
      const float ev = __expf(tile[tid][c]*0.125f - mx);
      tile[tid][c] = ev;
      ssum += ev;
    }
    invs[tid] = 1.0f / ssum;
  }
  __syncthreads();
  // transposed write: thread e writes attnT[e][0..63] contiguous
  if (tid < 64) {
    bf16_t* ao = attnT + (size_t)bh * D_ * D_ + tid * D_;
    #pragma unroll
    for (int d0 = 0; d0 < 64; d0 += 8) {
      bf16x8 vv;
      #pragma unroll
      for (int i = 0; i < 8; ++i) vv[i] = (bf16_t)(tile[d0+i][tid] * invs[d0+i]);
      *(bf16x8*)&ao[d0] = vv;
    }
  }
}

// ---------------------------------------------------------------- stage 3: W' compose
// w2t[b][j][h*64+e] = sum_d woutT[j][h*64+d] * attnT[bh][e][d]
// grid (6, B*H), 256 threads (4 waves x 32 j-rows each)
__global__ __launch_bounds__(256, 2)
void compose_w2(const bf16_t* __restrict__ woutT, const bf16_t* __restrict__ attnT,
                bf16_t* __restrict__ w2t)
{
  const int jb = blockIdx.x;
  const int bh = blockIdx.y;
  const int b = bh / H_, h = bh - b*H_;
  const int tid = threadIdx.x, wave = tid >> 6, lane = tid & 63;
  const int fr = lane & 15, fo = (lane >> 4) * 8;
  const bf16_t* at = attnT + (size_t)bh * D_ * D_;
  f32x4 acc[2][4] = {{0.f,0.f,0.f,0.f}};
  #pragma unroll
  for (int kk = 0; kk < 2; ++kk) {
    bf16x8 af[2], bfv[4];
    #pragma unroll
    for (int m = 0; m < 2; ++m)
      af[m] = *(const bf16x8*)&woutT[(size_t)(jb*128 + wave*32 + m*16 + fr)*C_ + h*64 + kk*32 + fo];
    #pragma unroll
    for (int n = 0; n < 4; ++n)
      bfv[n] = *(const bf16x8*)&at[(n*16 + fr)*64 + kk*32 + fo];
    #pragma unroll
    for (int m = 0; m < 2; ++m)
      #pragma unroll
      for (int n = 0; n < 4; ++n)
        acc[m][n] = MFMA16(af[m], bfv[n], acc[m][n]);
  }
  bf16_t* wb = w2t + (size_t)b * C_ * C_;
  #pragma unroll
  for (int m = 0; m < 2; ++m) {
    const int j = jb*128 + wave*32 + m*16 + ((lane >> 4) << 2);
    #pragma unroll
    for (int n = 0; n < 4; ++n) {
      const int e = n*16 + fr;
      #pragma unroll
      for (int jj = 0; jj < 4; ++jj)
        wb[(size_t)(j + jj)*C_ + h*64 + e] = (bf16_t)acc[m][n][jj];
    }
  }
}

// ---------------------------------------------------------------- launcher
extern "C" void kernel_launch(void* const* d_in, const int* in_sizes, int n_in,
                              void* d_out, int out_size, void* d_ws, size_t ws_size,
                              hipStream_t stream)
{
  (void)in_sizes; (void)n_in; (void)out_size;
  const float* x     = (const float*)d_in[0];
  const float* w_qkv = (const float*)d_in[1];
  const float* b_qkv = (const float*)d_in[2];
  const float* w_out = (const float*)d_in[3];
  const float* b_out = (const float*)d_in[4];
  float* out = (float*)d_out;

  const size_t sz_xb   = (size_t)M_*C_*2;        // 50.3 MB
  const size_t sz_wq   = (size_t)TC_*C_*2;       //  3.5 MB
  const size_t sz_wo   = (size_t)C_*C_*2;        //  1.2 MB
  const size_t sz_qh   = (size_t)B_*H_*N_*D_*2;  // 50.3 MB
  const size_t sz_kv   = (size_t)B_*H_*D_*N_*2;  // 50.3 MB each
  const size_t sz_attn = (size_t)B_*H_*D_*D_*2;  //  3.1 MB

  char* p = (char*)d_ws;
  bf16_t* xb    = (bf16_t*)p; p += sz_xb;
  bf16_t* wqkvT = (bf16_t*)p; p += sz_wq;
  bf16_t* woutT = (bf16_t*)p; p += sz_wo;
  bf16_t* qh    = (bf16_t*)p; p += sz_qh;
  bf16_t* kthi  = (bf16_t*)p; p += sz_kv;
  bf16_t* vthi  = (bf16_t*)p; p += sz_kv;
  bf16_t* attnT = (bf16_t*)p; p += sz_attn;
  const size_t base_need = (size_t)(p - (char*)d_ws);
  // W' (32 x 768 x 768 bf16 = 37.7 MB) aliases xb (50.3 MB), dead after GEMM1
  bf16_t* w2t = xb;

  if (ws_size < base_need) return;   // leaves poison -> distinctive failure

  cvt_bf16<<<dim3((M_*C_)/2048), 256, 0, stream>>>(x, xb, M_*C_);
  transpose_cvt<<<dim3(TC_/32, C_/32), 256, 0, stream>>>(w_qkv, wqkvT, C_, TC_);
  transpose_cvt<<<dim3(C_/32,  C_/32), 256, 0, stream>>>(w_out, woutT, C_, C_);

  // GEMM1: qkv projection with scatter epilogue. grid = 9 x 128 = 1152 (8 | 1152)
  gemm_bt<1><<<dim3((TC_/256)*(M_/256)), 512, 0, stream>>>(
      xb, wqkvT, b_qkv, nullptr, qh, kthi, vthi, TC_/256);

  attn_softmax_k<<<dim3(B_*H_), 256, 0, stream>>>(kthi, vthi, attnT);

  compose_w2<<<dim3(C_/128, B_*H_), 256, 0, stream>>>(woutT, attnT, w2t);

  // GEMM2: out = qh(gathered) @ W'_b + b_out. grid = 6 x 256 = 1536 (6 exact rounds)
  gemm2_128<<<dim3((C_/128)*(M_/128)), 256, 0, stream>>>(
      qh, w2t, b_out, out, C_/128);
}